// Round 7
// baseline (248.399 us; speedup 1.0000x reference)
//
#include <hip/hip_runtime.h>
#include <stdint.h>

#define N_S 30000
#define N_G 3000
#define DD  128
#define KK  16
#define NE  (N_G * KK)
#define NC  16            // cells per axis
#define CELLS (NC * NC * NC)
#define CH  3.75f         // cell size (60/16), exactly representable
#define CAP 16            // slots per cell; overflow list keeps exactness
#define SURV 384          // survivor buffer capacity (covers R=2 worst ~317)
#define ECAP 32           // incoming-edge slots per surface node (Poisson(1.6))
#define EOVF_CAP 8192     // spill list for >ECAP rows (exactness net)

#define FILL_BLOCKS 118   // ceil(30000/256)
#define PACK_BLOCKS 384   // 768 weight-row tasks, 2 per block
#define NBS16 1875        // 30000/16 pre tiles (s)
#define NBG16 188         // ceil(3000/16) pre tiles (g)
#define PRE_TILES (NBS16 + NBG16)   // 2063
#define TASKS 5160        // 1032 groups of 5 wave-tasks: 3 kNN + 2 pre
#define QBLOCKS 768       // persistent 4-wave blocks feeding off the queue
#define NBS 469           // ceil(30000/64) post tiles (s)
#define NBG 47            // ceil(3000/64) post tiles (g)
#define NTILE (NBS + NBG) // 516

typedef unsigned long long ull;
// key = (f32 d2 bits << 32) | sid : unsigned order == lex (d2, sid) order
#define INF_KEY 0x7F7FFFFF7FFFFFFFull   // d2 = FLT_MAX, sid = INT_MAX

using v8s = __attribute__((ext_vector_type(8))) short;   // 8 bf16 (4 VGPRs)
using v4f = __attribute__((ext_vector_type(4))) float;   // MFMA accumulator

__device__ __forceinline__ float bf2f(unsigned short u) {
    union { unsigned int i; float f; } v; v.i = ((unsigned int)u) << 16; return v.f;
}
__device__ __forceinline__ unsigned short f2bf(float f) {
    union { float f; unsigned int i; } v; v.f = f;
    unsigned int x = v.i;
    return (unsigned short)((x + 0x7fffu + ((x >> 16) & 1u)) >> 16);
}
__device__ __forceinline__ float ldIn(const void* p, int i, int bf) {
    return bf ? bf2f(((const unsigned short*)p)[i]) : ((const float*)p)[i];
}
__device__ __forceinline__ void stOut(void* p, int i, float v, int bf) {
    if (bf) ((unsigned short*)p)[i] = f2bf(v);
    else    ((float*)p)[i] = v;
}
__device__ __forceinline__ int cellOf(float x) {
    int c = (int)(x * (1.0f / CH));
    if (c < 0) c = 0; if (c > NC - 1) c = NC - 1;
    return c;
}
__device__ __forceinline__ float dist2(float gx, float gy, float gz, float4 cd) {
    const float dx = gx - cd.x, dy = gy - cd.y, dz = gz - cd.z;
    return fmaf(dx, dx, fmaf(dy, dy, dz * dz));
}
__device__ __forceinline__ ull packKey(float d2, int sid) {
    return ((ull)__float_as_uint(d2) << 32) | (unsigned)sid;
}

// Inline dtype probe: 16 u32 words of pos_g; bf16 low-halves in [0.25,64) put
// (w>>8)&0xFF in [0x3E,0x42]; f32 mantissa bytes ~uniform (0-1 votes of 16).
__device__ __forceinline__ int detectFlag(const void* pos_g) {
    const unsigned int* w = (const unsigned int*)pos_g;
    int votes = 0;
#pragma unroll
    for (int i = 0; i < 16; ++i) {
        const unsigned int b = (w[i] >> 8) & 0xFFu;
        votes += (b >= 0x3Eu && b <= 0x42u) ? 1 : 0;
    }
    return votes >= 8;
}

// Emit one kNN result: outputs for the g-side gather AND a slotted incoming-
// edge record for the surface row (consumed by the fused post kernel).
__device__ __forceinline__ void emitEdge(int g, ull key, int rank,
                                         int* __restrict__ idx_out,
                                         float* __restrict__ w_out,
                                         int* __restrict__ scnt,
                                         int2* __restrict__ edge,
                                         int4* __restrict__ eovf,
                                         int* __restrict__ neovf)
{
    const int sid = (int)(unsigned)key;
    const float d2 = __uint_as_float((unsigned)(key >> 32));
    const float wv = expf(-d2 * (1.0f / 12.5f));
    idx_out[g * KK + rank] = sid;
    w_out[g * KK + rank] = wv;
    const int c = atomicAdd(&scnt[sid], 1);
    if (c < ECAP) {
        edge[(size_t)sid * ECAP + c] = make_int2(g, __float_as_int(wv));
    } else {
        const int o = atomicAdd(neovf, 1);
        if (o < EOVF_CAP) eovf[o] = make_int4(sid, g, __float_as_int(wv), 0);
    }
}

// 16-deep sorted insert (u64 lex keys). Guard rejects most keys cheaply.
__device__ __forceinline__ void ins16(ull key, ull bk[KK]) {
    if (key >= bk[KK - 1]) return;
    ull c = key;
#pragma unroll
    for (int j = 0; j < KK; ++j) {
        const bool less = c < bk[j];
        const ull nk = less ? c : bk[j];
        const ull ok = less ? bk[j] : c;
        bk[j] = nk; c = ok;
    }
}

// m(R) = min distance from query to any UNCLIPPED boundary face of the
// (2R+1)^3 cell region clipped to the box; every unscanned point is at
// distance >= m(R). Clipped faces (box wall) contribute infinity.
template<int R>
__device__ __forceinline__ float regionM2f(float gx, float gy, float gz,
                                           int cx, int cy, int cz)
{
    float m = 1e30f;
    if (cx - R > 0)      m = fminf(m, gx - (float)(cx - R) * CH);
    if (cx + R < NC - 1) m = fminf(m, (float)(cx + R + 1) * CH - gx);
    if (cy - R > 0)      m = fminf(m, gy - (float)(cy - R) * CH);
    if (cy + R < NC - 1) m = fminf(m, (float)(cy + R + 1) * CH - gy);
    if (cz - R > 0)      m = fminf(m, gz - (float)(cz - R) * CH);
    if (cz + R < NC - 1) m = fminf(m, (float)(cz + R + 1) * CH - gz);
    m = fmaxf(m, 0.f);
    return (m < 1e29f) ? m * m * (1.0f - 1e-5f) : 1e30f;
}

// ---------------------------------------------------------------------------
// Region scan at compile-time radius R: two lanes per cell, up to 8
// independent scell loads per lane per pass, survivors (d2 < m2eff)
// compacted into this wave's LDS slice via wave prefix-scan. Returns
// survivor count (may exceed SURV -> caller falls back). Buffer order
// irrelevant: ranks are computed from values; the u64 key is a total order.
// ---------------------------------------------------------------------------
template<int R>
__device__ int scanR(int t, float gx, float gy, float gz,
                     int cx, int cy, int cz, float m2eff,
                     const int* __restrict__ ccnt,
                     const float4* __restrict__ scell,
                     const float4* __restrict__ ovf, int novf,
                     ull* __restrict__ skey)
{
    const int S = 2 * R + 1;
    const int S3 = S * S * S;
    int total = 0;

    for (int b0 = 0; b0 < 2 * S3; b0 += 64) {
        const int pt = b0 + t;
        int cnt = 0, base = 0;
        if (pt < 2 * S3) {
            const int cell = pt >> 1, h = pt & 1;      // S constexpr -> fast div
            const int dx = cell / (S * S) - R;
            const int dy = (cell / S) % S - R;
            const int dz = cell % S - R;
            const int X = cx + dx, Y = cy + dy, Z = cz + dz;
            if (X >= 0 && X < NC && Y >= 0 && Y < NC && Z >= 0 && Z < NC) {
                const int cid = (X * NC + Y) * NC + Z;
                int c = ccnt[cid]; if (c > CAP) c = CAP;
                const int lo = h * 8;
                const int hi = (c < lo + 8) ? c : (lo + 8);
                cnt = (hi > lo) ? (hi - lo) : 0;
                base = cid * CAP + lo;
            }
        }
        // one parallel load round: up to 8 independent scell loads per lane
        ull kv[8]; int okm = 0;
#pragma unroll
        for (int i = 0; i < 8; ++i) {
            kv[i] = 0;
            if (i < cnt) {
                const float4 cd = scell[base + i];
                const float d2 = dist2(gx, gy, gz, cd);
                if (d2 < m2eff) { okm |= (1 << i); kv[i] = packKey(d2, __float_as_int(cd.w)); }
            }
        }
        int myc = __popc(okm);
        int incl = myc;
        for (int d = 1; d < 64; d <<= 1) {
            int v = __shfl_up(incl, d);
            if (t >= d) incl += v;
        }
        int pos = total + (incl - myc);
        total += __shfl(incl, 63);
#pragma unroll
        for (int i = 0; i < 8; ++i) {
            if (okm & (1 << i)) {
                if (pos < SURV) skey[pos] = kv[i];
                ++pos;
            }
        }
        if (total > SURV) return total;   // overflow -> exactness net
    }

    // cell-overflow points (few; usually zero)
    for (int i0 = 0; i0 < novf; i0 += 64) {
        const int i = i0 + t;
        bool act = (i < novf);
        ull key = 0;
        if (act) {
            const float4 cd = ovf[i];
            const float d2 = dist2(gx, gy, gz, cd);
            act = (d2 < m2eff);
            if (act) key = packKey(d2, __float_as_int(cd.w));
        }
        const ull b = __ballot(act);
        const int p2 = total + (int)__popcll(b & ((1ull << t) - 1ull));
        if (act && p2 < SURV) skey[p2] = key;
        total += (int)__popcll(b);
    }
    return total;
}

// Exact global ranks: each lane's <=NV survivors vs all j, single u64
// compare per j. skey[j] reads are wave-uniform -> LDS broadcast.
template<int NV>
__device__ void rankEmit(int t, int n, const ull* __restrict__ skey, int g,
                         int* __restrict__ idx_out, float* __restrict__ w_out,
                         int* __restrict__ scnt, int2* __restrict__ edge,
                         int4* __restrict__ eovf, int* __restrict__ neovf)
{
    // single wave: LDS fence is enough (no full barrier round-trip)
    asm volatile("s_waitcnt lgkmcnt(0)" ::: "memory");
    ull ki[NV]; int rk[NV]; int nv = 0;
    for (int i = t; i < n && nv < NV; i += 64) { ki[nv] = skey[i]; rk[nv] = 0; ++nv; }
    for (int j = 0; j < n; ++j) {
        const ull kj = skey[j];
#pragma unroll
        for (int q = 0; q < NV; ++q)
            if (q < nv) rk[q] += (kj < ki[q]) ? 1 : 0;
    }
#pragma unroll
    for (int q = 0; q < NV; ++q)
        if (q < nv && rk[q] < KK)
            emitEdge(g, ki[q], rk[q], idx_out, w_out, scnt, edge, eovf, neovf);
}

// ---------------------------------------------------------------------------
// Exactness net (probability ~0): wave-local brute force over all N_S
// points — per-lane guarded sorted insert + 16 destructive wave-min
// butterflies. Barrier-free (safe in per-wave-divergent multi-wave blocks).
// ---------------------------------------------------------------------------
__attribute__((noinline))
__device__ void knn_brute(int g, int t, int bf,
                          const void* pos_g, const void* pos_s,
                          int* __restrict__ idx_out, float* __restrict__ w_out,
                          int* __restrict__ scnt, int2* __restrict__ edge,
                          int4* __restrict__ eovf, int* __restrict__ neovf)
{
    const float gx = ldIn(pos_g, 3 * g + 0, bf);
    const float gy = ldIn(pos_g, 3 * g + 1, bf);
    const float gz = ldIn(pos_g, 3 * g + 2, bf);

    ull bk[KK];
#pragma unroll
    for (int j = 0; j < KK; ++j) bk[j] = INF_KEY;

    for (int i = t; i < N_S; i += 64) {
        const float dx = gx - ldIn(pos_s, 3 * i + 0, bf);
        const float dy = gy - ldIn(pos_s, 3 * i + 1, bf);
        const float dz = gz - ldIn(pos_s, 3 * i + 2, bf);
        const float d2 = fmaf(dx, dx, fmaf(dy, dy, dz * dz));
        ins16(packKey(d2, i), bk);
    }

    ull myKey = INF_KEY;
    for (int p = 0; p < KK; ++p) {
        ull key = bk[0];
        for (int d = 1; d < 64; d <<= 1) {
            const ull ok = __shfl_xor(key, d);
            if (ok < key) key = ok;
        }
        if (t == p) myKey = key;
        if (bk[0] == key) {        // unique sids -> unique keys
#pragma unroll
            for (int j = 0; j < KK - 1; ++j) bk[j] = bk[j + 1];
            bk[KK - 1] = INF_KEY;
        }
    }
    if (t < KK)
        emitEdge(g, myKey, t, idx_out, w_out, scnt, edge, eovf, neovf);
}

// One kNN node, one wave, barrier-free.
__device__ void knn_task(int g, int t, int bf,
                         const void* pos_g, const void* pos_s,
                         const int* __restrict__ ccnt,
                         const float4* __restrict__ scell,
                         const float4* __restrict__ ovf, int novf,
                         int* __restrict__ idx, float* __restrict__ w,
                         int* __restrict__ scnt, int2* __restrict__ edge,
                         int4* __restrict__ eovf, int* __restrict__ neovf,
                         ull* __restrict__ skey)
{
    const float gx = ldIn(pos_g, 3 * g + 0, bf);
    const float gy = ldIn(pos_g, 3 * g + 1, bf);
    const float gz = ldIn(pos_g, 3 * g + 2, bf);
    const int cx = cellOf(gx), cy = cellOf(gy), cz = cellOf(gz);

    int total = scanR<1>(t, gx, gy, gz, cx, cy, cz,
                         regionM2f<1>(gx, gy, gz, cx, cy, cz),
                         ccnt, scell, ovf, novf, skey);
    if (total < KK)                      // clipped sphere near box face
        total = scanR<2>(t, gx, gy, gz, cx, cy, cz,
                         regionM2f<2>(gx, gy, gz, cx, cy, cz),
                         ccnt, scell, ovf, novf, skey);

    if (total >= KK && total <= SURV) {
        if (total <= 192)
            rankEmit<3>(t, total, skey, g, idx, w, scnt, edge, eovf, neovf);
        else
            rankEmit<6>(t, total, skey, g, idx, w, scnt, edge, eovf, neovf);
    } else {                             // exactness net (~never)
        knn_brute(g, t, bf, pos_g, pos_s, idx, w, scnt, edge, eovf, neovf);
    }
}

// ---- MFMA helpers -------------------------------------------------------
__device__ __forceinline__ v8s loadA_bf16(const unsigned short* p) {
    return *(const v8s*)p;
}
__device__ __forceinline__ v8s loadA_f32v(const float* f) {
    const float4 a = *(const float4*)f;
    const float4 b = *(const float4*)(f + 4);
    v8s r;
    r[0] = (short)f2bf(a.x); r[1] = (short)f2bf(a.y);
    r[2] = (short)f2bf(a.z); r[3] = (short)f2bf(a.w);
    r[4] = (short)f2bf(b.x); r[5] = (short)f2bf(b.y);
    r[6] = (short)f2bf(b.z); r[7] = (short)f2bf(b.w);
    return r;
}
__device__ __forceinline__ v8s loadA_raw(const void* A, size_t off, int bf) {
    if (bf) return loadA_bf16((const unsigned short*)A + off);
    return loadA_f32v((const float*)A + off);
}

// pre tile, ONE WAVE: 16 rows x 128 cols, K=128. Barrier-free.
__device__ void pre_tile16(int task, int lane, int bf, const void* xs, const void* xg,
                           const unsigned short* __restrict__ wpk_ps,
                           const unsigned short* __restrict__ wpk_pg,
                           unsigned short* __restrict__ hsb,
                           unsigned short* __restrict__ hgb)
{
    const void* A; const unsigned short* wpk; unsigned short* outp; int M, m0;
    const bool is_s = (task < NBS16);
    if (is_s) { A = xs; wpk = wpk_ps; outp = hsb; M = N_S; m0 = task * 16; }
    else      { A = xg; wpk = wpk_pg; outp = hgb; M = N_G; m0 = (task - NBS16) * 16; }

    const int q = lane >> 4, lm = lane & 15;
    const int mrow = m0 + lm;
    const bool valid = (mrow < M);

    v4f acc[8];
#pragma unroll
    for (int t = 0; t < 8; ++t) acc[t] = {0.f, 0.f, 0.f, 0.f};
    for (int ks = 0; ks < 4; ++ks) {
        v8s a = {0,0,0,0,0,0,0,0};
        if (valid) a = loadA_raw(A, (size_t)mrow * 128 + ks * 32 + q * 8, bf);
        const unsigned short* wb = wpk + (size_t)(ks * 4 + q) * 128 * 8;
#pragma unroll
        for (int t = 0; t < 8; ++t) {
            const v8s bfr = *(const v8s*)(wb + (t * 16 + lm) * 8);
            acc[t] = __builtin_amdgcn_mfma_f32_16x16x32_bf16(a, bfr, acc[t], 0, 0, 0);
        }
    }
#pragma unroll
    for (int t = 0; t < 8; ++t)
#pragma unroll
        for (int r = 0; r < 4; ++r) {
            const int row = m0 + q * 4 + r;
            if (row < M) outp[(size_t)row * 128 + t * 16 + lm] = f2bf(acc[t][r]);
        }
}

// post tile: 64 rows x 128 cols, K=256, 256 threads (4 waves).
// A2 (rows 128..255 of the concat) is built ONCE per lane into registers
// (all four 8-col slices in a single edge pass), then fed to the MFMA loop:
//   s-rows: sum over slotted incoming edges (g, w) of w * hg[g]  (hg L2-hot)
//   g-rows: sum over the node's K edges of w * hs[idx]           (gather)
__device__ void post_tile(int task, int bf,
                          const unsigned short* __restrict__ hsb,
                          const unsigned short* __restrict__ hgb,
                          const int* __restrict__ scnt,
                          const int2* __restrict__ edge,
                          const int4* __restrict__ eovf, int nov2,
                          const int* __restrict__ idx, const float* __restrict__ w,
                          const unsigned short* __restrict__ wpk_cs,
                          const unsigned short* __restrict__ wpk_cg,
                          void* out)
{
    const unsigned short* A1; const unsigned short* wpk;
    int M, m0, ooff;
    const bool is_s = (task < NBS);
    if (is_s) { A1 = hsb; wpk = wpk_cs; M = N_S; m0 = task * 64; ooff = 0; }
    else      { A1 = hgb; wpk = wpk_cg; M = N_G; m0 = (task - NBS) * 64; ooff = N_S * DD; }

    const int wave = threadIdx.x >> 6, lane = threadIdx.x & 63;
    const int q = lane >> 4, lm = lane & 15;
    const int mb = m0 + wave * 16;
    const int mrow = mb + lm;
    const bool valid = (mrow < M);

    // ---- build this lane's four A2 slices (cols 128 + si*32 + q*8 .. +8) ----
    v8s a2[4];
    if (valid) {
        float f[4][8];
#pragma unroll
        for (int si = 0; si < 4; ++si)
#pragma unroll
            for (int j = 0; j < 8; ++j) f[si][j] = 0.f;
        if (is_s) {
            const int c = scnt[mrow];
            const int cc = (c < ECAP) ? c : ECAP;
            for (int e = 0; e < cc; ++e) {
                const int2 ed = edge[(size_t)mrow * ECAP + e];
                const float we = __int_as_float(ed.y);
                const unsigned short* hrow = hgb + (size_t)ed.x * 128 + q * 8;
#pragma unroll
                for (int si = 0; si < 4; ++si) {
                    const v8s hv = *(const v8s*)(hrow + si * 32);
#pragma unroll
                    for (int j = 0; j < 8; ++j)
                        f[si][j] += we * bf2f((unsigned short)hv[j]);
                }
            }
            if (c > ECAP) {                // exactness net (~never)
                for (int e = 0; e < nov2; ++e) {
                    const int4 ov = eovf[e];
                    if (ov.x == mrow) {
                        const float we = __int_as_float(ov.z);
                        const unsigned short* hrow = hgb + (size_t)ov.y * 128 + q * 8;
#pragma unroll
                        for (int si = 0; si < 4; ++si) {
                            const v8s hv = *(const v8s*)(hrow + si * 32);
#pragma unroll
                            for (int j = 0; j < 8; ++j)
                                f[si][j] += we * bf2f((unsigned short)hv[j]);
                        }
                    }
                }
            }
        } else {
            for (int e = 0; e < KK; ++e) {
                const int gi = idx[mrow * KK + e];
                const float we = w[mrow * KK + e];
                const unsigned short* hrow = hsb + (size_t)gi * 128 + q * 8;
#pragma unroll
                for (int si = 0; si < 4; ++si) {
                    const v8s hv = *(const v8s*)(hrow + si * 32);
#pragma unroll
                    for (int j = 0; j < 8; ++j)
                        f[si][j] += we * bf2f((unsigned short)hv[j]);
                }
            }
        }
#pragma unroll
        for (int si = 0; si < 4; ++si) {
            v8s r;
#pragma unroll
            for (int j = 0; j < 8; ++j) r[j] = (short)f2bf(f[si][j]);
            a2[si] = r;
        }
    } else {
#pragma unroll
        for (int si = 0; si < 4; ++si) a2[si] = (v8s){0,0,0,0,0,0,0,0};
    }

    v4f acc[8];
#pragma unroll
    for (int t = 0; t < 8; ++t) acc[t] = {0.f, 0.f, 0.f, 0.f};
#pragma unroll
    for (int ks = 0; ks < 8; ++ks) {
        const int kk = ks * 32 + q * 8;
        v8s a;
        if (ks < 4) {
            a = (v8s){0,0,0,0,0,0,0,0};
            if (valid) a = loadA_bf16(A1 + (size_t)mrow * 128 + kk);
        } else {
            a = a2[ks - 4];                // compile-time index (loop unrolled)
        }
        const unsigned short* wb = wpk + (size_t)(ks * 4 + q) * 128 * 8;
#pragma unroll
        for (int t = 0; t < 8; ++t) {
            const v8s bfr = *(const v8s*)(wb + (t * 16 + lm) * 8);
            acc[t] = __builtin_amdgcn_mfma_f32_16x16x32_bf16(a, bfr, acc[t], 0, 0, 0);
        }
    }
#pragma unroll
    for (int t = 0; t < 8; ++t)
#pragma unroll
        for (int r = 0; r < 4; ++r) {
            const int row = mb + q * 4 + r;
            if (row < M) {
                float v = acc[t][r];
                if (v < 0.f) v = 0.f;
                stOut(out, ooff + row * DD + t * 16 + lm, v, bf);
            }
        }
}

// ---------------------------------------------------------------------------
// Dispatch 2: blocks 0..117 bin surface points; blocks 118..501 pack weights.
// ---------------------------------------------------------------------------
__global__ __launch_bounds__(256) void fill_pack_kernel(
    const void* pos_s, const void* pos_g,
    const void* Wsp, const void* Wgp, const void* Wgs, const void* Wsg,
    const void* Wspost, const void* Wgpost,
    int* __restrict__ ccnt, float4* __restrict__ scell,
    float4* __restrict__ ovf, int* __restrict__ novf,
    unsigned short* __restrict__ wpk_ps, unsigned short* __restrict__ wpk_pg,
    unsigned short* __restrict__ wpk_cs, unsigned short* __restrict__ wpk_cg)
{
    const int bf = detectFlag(pos_g);
    const int bid = blockIdx.x, tid = threadIdx.x;
    if (bid < FILL_BLOCKS) {
        const int p = bid * 256 + tid;
        if (p < N_S) {
            const float x = ldIn(pos_s, 3 * p + 0, bf);
            const float y = ldIn(pos_s, 3 * p + 1, bf);
            const float z = ldIn(pos_s, 3 * p + 2, bf);
            const int cid = (cellOf(x) * NC + cellOf(y)) * NC + cellOf(z);
            const int slot = atomicAdd(&ccnt[cid], 1);
            const float4 pt = make_float4(x, y, z, __int_as_float(p));
            if (slot < CAP) scell[cid * CAP + slot] = pt;
            else            ovf[atomicAdd(novf, 1)] = pt;
        }
        return;
    }
    __shared__ float rows[256];
    const int rt = bid - FILL_BLOCKS;            // 0..383
    const int half = tid >> 7, j = tid & 127;
    const int task = rt * 2 + half;              // 0..767; branch uniform per block
    float v; unsigned short* dst; int k;
    if (task < 128) { k = task; v = ldIn(Wsp, k * DD + j, bf); dst = wpk_ps; }
    else if (task < 256) { k = task - 128; v = ldIn(Wgp, k * DD + j, bf); dst = wpk_pg; }
    else {
        const int which_g = (task >= 512);
        const int r = which_g ? (task - 512) : (task - 256);
        const void* W1 = which_g ? Wsg : Wgs;
        const void* Wp = which_g ? Wgpost : Wspost;
        dst = which_g ? wpk_cg : wpk_cs;
        k = r;
        if (r < 128) v = ldIn(Wp, r * DD + j, bf);
        else {
            rows[half * 128 + j] = ldIn(W1, (r - 128) * DD + j, bf);
            __syncthreads();
            float acc = 0.f;
            for (int m = 0; m < DD; ++m)
                acc += rows[half * 128 + m] * ldIn(Wp, (DD + m) * DD + j, bf);
            v = acc;
        }
    }
    const int ks = k >> 5, q = (k >> 3) & 3, i = k & 7;
    dst[((ks * 4 + q) * 128 + j) * 8 + i] = f2bf(v);
}

// ---------------------------------------------------------------------------
// Dispatch 3: QBLOCKS persistent 4-wave blocks; each WAVE loops grabbing
// wave-tasks (3 kNN : 2 pre interleave) from a global atomic queue.
// Removes the ~25-cyc/WG command-processor launch bottleneck that capped
// the old 5160-tiny-WG grid at ~3.5 resident waves/CU. Zero barriers.
// ---------------------------------------------------------------------------
__global__ __launch_bounds__(256) void knn_pre_kernel(
    const void* xs, const void* xg, const void* pos_s, const void* pos_g,
    const int* __restrict__ ccnt, const float4* __restrict__ scell,
    const float4* __restrict__ ovf, const int* __restrict__ novf,
    int* __restrict__ idx, float* __restrict__ w,
    int* __restrict__ scnt, int2* __restrict__ edge,
    int4* __restrict__ eovf, int* __restrict__ neovf,
    int* __restrict__ qctr,
    const unsigned short* __restrict__ wpk_ps,
    const unsigned short* __restrict__ wpk_pg,
    unsigned short* __restrict__ hsb, unsigned short* __restrict__ hgb)
{
    __shared__ ull skey[4][SURV];
    const int bf = detectFlag(pos_g);
    const int wv = threadIdx.x >> 6, lane = threadIdx.x & 63;
    const int nov = *novf;

    for (;;) {
        int t0 = 0;
        if (lane == 0) t0 = atomicAdd(qctr, 1);
        t0 = __shfl(t0, 0);                 // wave-uniform task id
        if (t0 >= TASKS) break;
        const int grp = t0 / 5, off = t0 - grp * 5;
        if (off < 3) {
            const int g = grp * 3 + off;
            if (g < N_G)
                knn_task(g, lane, bf, pos_g, pos_s, ccnt, scell, ovf, nov,
                         idx, w, scnt, edge, eovf, neovf, skey[wv]);
        } else {
            const int task = grp * 2 + (off - 3);
            if (task < PRE_TILES)
                pre_tile16(task, lane, bf, xs, xg, wpk_ps, wpk_pg, hsb, hgb);
        }
    }
}

// Dispatch 4: post GEMMs with fused message aggregation.
__global__ __launch_bounds__(256) void mfma_post_kernel(
    const void* pos_g,
    const unsigned short* __restrict__ hsb, const unsigned short* __restrict__ hgb,
    const int* __restrict__ scnt, const int2* __restrict__ edge,
    const int4* __restrict__ eovf, const int* __restrict__ neovf,
    const int* __restrict__ idx, const float* __restrict__ w,
    const unsigned short* __restrict__ wpk_cs, const unsigned short* __restrict__ wpk_cg,
    void* out)
{
    const int bf = detectFlag(pos_g);
    int nov2 = *neovf; if (nov2 > EOVF_CAP) nov2 = EOVF_CAP;
    post_tile(blockIdx.x, bf, hsb, hgb, scnt, edge, eovf, nov2,
              idx, w, wpk_cs, wpk_cg, out);
}

extern "C" void kernel_launch(void* const* d_in, const int* in_sizes, int n_in,
                              void* d_out, int out_size, void* d_ws, size_t ws_size,
                              hipStream_t stream)
{
    const void* xs       = d_in[0];
    const void* xg       = d_in[1];
    const void* pos_s    = d_in[2];
    const void* pos_g    = d_in[3];
    const void* W_s_pre  = d_in[4];
    const void* W_g_pre  = d_in[5];
    const void* W_gs     = d_in[6];
    const void* W_sg     = d_in[7];
    const void* W_s_post = d_in[8];
    const void* W_g_post = d_in[9];
    (void)in_sizes; (void)n_in; (void)out_size; (void)ws_size;

    char* ws = (char*)d_ws;
    size_t off_b = 0;
    auto alloc = [&](size_t bytes) -> void* {
        void* p = ws + off_b;
        off_b = (off_b + bytes + 255) & ~((size_t)255);
        return p;
    };
    unsigned short* hsb    = (unsigned short*)alloc((size_t)N_S * DD * 2);
    unsigned short* hgb    = (unsigned short*)alloc((size_t)N_G * DD * 2);
    unsigned short* wpk_ps = (unsigned short*)alloc((size_t)DD * DD * 2);
    unsigned short* wpk_pg = (unsigned short*)alloc((size_t)DD * DD * 2);
    unsigned short* wpk_cs = (unsigned short*)alloc((size_t)2 * DD * DD * 2);
    unsigned short* wpk_cg = (unsigned short*)alloc((size_t)2 * DD * DD * 2);
    int*            idx    = (int*)   alloc((size_t)NE * 4);
    float*          w      = (float*) alloc((size_t)NE * 4);
    // contiguous zeroed block: ccnt | novf | scnt | neovf | qctr
    int*            ibase  = (int*)   alloc((size_t)(CELLS + 1 + N_S + 2) * 4);
    int*            ccnt   = ibase;
    int*            novf   = ibase + CELLS;
    int*            scnt   = ibase + CELLS + 1;
    int*            neovf  = ibase + CELLS + 1 + N_S;
    int*            qctr   = ibase + CELLS + 1 + N_S + 1;
    float4*         scell  = (float4*)alloc((size_t)CELLS * CAP * 16);
    float4*         ovf    = (float4*)alloc((size_t)N_S * 16);
    int2*           edge   = (int2*)  alloc((size_t)N_S * ECAP * 8);
    int4*           eovf   = (int4*)  alloc((size_t)EOVF_CAP * 16);

    hipMemsetAsync(ibase, 0, (size_t)(CELLS + 1 + N_S + 2) * 4, stream);

    fill_pack_kernel<<<FILL_BLOCKS + PACK_BLOCKS, 256, 0, stream>>>(
        pos_s, pos_g, W_s_pre, W_g_pre, W_gs, W_sg, W_s_post, W_g_post,
        ccnt, scell, ovf, novf, wpk_ps, wpk_pg, wpk_cs, wpk_cg);

    knn_pre_kernel<<<QBLOCKS, 256, 0, stream>>>(
        xs, xg, pos_s, pos_g, ccnt, scell, ovf, novf, idx, w,
        scnt, edge, eovf, neovf, qctr, wpk_ps, wpk_pg, hsb, hgb);

    mfma_post_kernel<<<NTILE, 256, 0, stream>>>(
        pos_g, hsb, hgb, scnt, edge, eovf, neovf, idx, w,
        wpk_cs, wpk_cg, d_out);
}

// Round 8
// 172.384 us; speedup vs baseline: 1.4410x; 1.4410x over previous
//
#include <hip/hip_runtime.h>
#include <stdint.h>

#define N_S 30000
#define N_G 3000
#define DD  128
#define KK  16
#define NE  (N_G * KK)
#define NC  16            // cells per axis
#define CELLS (NC * NC * NC)
#define CH  3.75f         // cell size (60/16), exactly representable
#define CAP 16            // slots per cell; overflow list keeps exactness
#define SURV 384          // survivor buffer capacity (covers R=2 worst ~317)
#define ECAP 32           // incoming-edge slots per surface node (Poisson(1.6))
#define EOVF_CAP 8192     // spill list for >ECAP rows (exactness net)

#define FILL_BLOCKS 118   // ceil(30000/256)
#define PACK_BLOCKS 384   // 768 weight-row tasks, 2 per block
#define NBS16 1875        // 30000/16 pre tiles (s)
#define NBG16 188         // ceil(3000/16) pre tiles (g)
#define PRE_TILES (NBS16 + NBG16)   // 2063
#define TASKS 5160        // 1032 groups of 5 wave-tasks: 3 kNN + 2 pre
#define QBLOCKS 768       // fat 4-wave blocks, static per-wave assignment
#define NWAVES (QBLOCKS * 4)        // 3072 worker waves
#define NBS 469           // ceil(30000/64) post tiles (s)
#define NBG 47            // ceil(3000/64) post tiles (g)
#define NTILE (NBS + NBG) // 516

typedef unsigned long long ull;
// key = (f32 d2 bits << 32) | sid : unsigned order == lex (d2, sid) order
#define INF_KEY 0x7F7FFFFF7FFFFFFFull   // d2 = FLT_MAX, sid = INT_MAX

using v8s = __attribute__((ext_vector_type(8))) short;   // 8 bf16 (4 VGPRs)
using v4f = __attribute__((ext_vector_type(4))) float;   // MFMA accumulator

__device__ __forceinline__ float bf2f(unsigned short u) {
    union { unsigned int i; float f; } v; v.i = ((unsigned int)u) << 16; return v.f;
}
__device__ __forceinline__ unsigned short f2bf(float f) {
    union { float f; unsigned int i; } v; v.f = f;
    unsigned int x = v.i;
    return (unsigned short)((x + 0x7fffu + ((x >> 16) & 1u)) >> 16);
}
__device__ __forceinline__ float ldIn(const void* p, int i, int bf) {
    return bf ? bf2f(((const unsigned short*)p)[i]) : ((const float*)p)[i];
}
__device__ __forceinline__ void stOut(void* p, int i, float v, int bf) {
    if (bf) ((unsigned short*)p)[i] = f2bf(v);
    else    ((float*)p)[i] = v;
}
__device__ __forceinline__ int cellOf(float x) {
    int c = (int)(x * (1.0f / CH));
    if (c < 0) c = 0; if (c > NC - 1) c = NC - 1;
    return c;
}
__device__ __forceinline__ float dist2(float gx, float gy, float gz, float4 cd) {
    const float dx = gx - cd.x, dy = gy - cd.y, dz = gz - cd.z;
    return fmaf(dx, dx, fmaf(dy, dy, dz * dz));
}
__device__ __forceinline__ ull packKey(float d2, int sid) {
    return ((ull)__float_as_uint(d2) << 32) | (unsigned)sid;
}

// Inline dtype probe: 16 u32 words of pos_g; bf16 low-halves in [0.25,64) put
// (w>>8)&0xFF in [0x3E,0x42]; f32 mantissa bytes ~uniform (0-1 votes of 16).
__device__ __forceinline__ int detectFlag(const void* pos_g) {
    const unsigned int* w = (const unsigned int*)pos_g;
    int votes = 0;
#pragma unroll
    for (int i = 0; i < 16; ++i) {
        const unsigned int b = (w[i] >> 8) & 0xFFu;
        votes += (b >= 0x3Eu && b <= 0x42u) ? 1 : 0;
    }
    return votes >= 8;
}

// Emit one kNN result: outputs for the g-side gather AND a slotted incoming-
// edge record for the surface row (consumed by the fused post kernel).
__device__ __forceinline__ void emitEdge(int g, ull key, int rank,
                                         int* __restrict__ idx_out,
                                         float* __restrict__ w_out,
                                         int* __restrict__ scnt,
                                         int2* __restrict__ edge,
                                         int4* __restrict__ eovf,
                                         int* __restrict__ neovf)
{
    const int sid = (int)(unsigned)key;
    const float d2 = __uint_as_float((unsigned)(key >> 32));
    const float wv = expf(-d2 * (1.0f / 12.5f));
    idx_out[g * KK + rank] = sid;
    w_out[g * KK + rank] = wv;
    const int c = atomicAdd(&scnt[sid], 1);
    if (c < ECAP) {
        edge[(size_t)sid * ECAP + c] = make_int2(g, __float_as_int(wv));
    } else {
        const int o = atomicAdd(neovf, 1);
        if (o < EOVF_CAP) eovf[o] = make_int4(sid, g, __float_as_int(wv), 0);
    }
}

// 16-deep sorted insert (u64 lex keys). Guard rejects most keys cheaply.
__device__ __forceinline__ void ins16(ull key, ull bk[KK]) {
    if (key >= bk[KK - 1]) return;
    ull c = key;
#pragma unroll
    for (int j = 0; j < KK; ++j) {
        const bool less = c < bk[j];
        const ull nk = less ? c : bk[j];
        const ull ok = less ? bk[j] : c;
        bk[j] = nk; c = ok;
    }
}

// m(R) = min distance from query to any UNCLIPPED boundary face of the
// (2R+1)^3 cell region clipped to the box; every unscanned point is at
// distance >= m(R). Clipped faces (box wall) contribute infinity.
template<int R>
__device__ __forceinline__ float regionM2f(float gx, float gy, float gz,
                                           int cx, int cy, int cz)
{
    float m = 1e30f;
    if (cx - R > 0)      m = fminf(m, gx - (float)(cx - R) * CH);
    if (cx + R < NC - 1) m = fminf(m, (float)(cx + R + 1) * CH - gx);
    if (cy - R > 0)      m = fminf(m, gy - (float)(cy - R) * CH);
    if (cy + R < NC - 1) m = fminf(m, (float)(cy + R + 1) * CH - gy);
    if (cz - R > 0)      m = fminf(m, gz - (float)(cz - R) * CH);
    if (cz + R < NC - 1) m = fminf(m, (float)(cz + R + 1) * CH - gz);
    m = fmaxf(m, 0.f);
    return (m < 1e29f) ? m * m * (1.0f - 1e-5f) : 1e30f;
}

// ---------------------------------------------------------------------------
// Region scan at compile-time radius R: two lanes per cell, up to 8
// independent scell loads per lane per pass, survivors (d2 < m2eff)
// compacted into this wave's LDS slice via wave prefix-scan. Returns
// survivor count (may exceed SURV -> caller falls back). Buffer order
// irrelevant: ranks are computed from values; the u64 key is a total order.
// ---------------------------------------------------------------------------
template<int R>
__device__ int scanR(int t, float gx, float gy, float gz,
                     int cx, int cy, int cz, float m2eff,
                     const int* __restrict__ ccnt,
                     const float4* __restrict__ scell,
                     const float4* __restrict__ ovf, int novf,
                     ull* __restrict__ skey)
{
    const int S = 2 * R + 1;
    const int S3 = S * S * S;
    int total = 0;

    for (int b0 = 0; b0 < 2 * S3; b0 += 64) {
        const int pt = b0 + t;
        int cnt = 0, base = 0;
        if (pt < 2 * S3) {
            const int cell = pt >> 1, h = pt & 1;      // S constexpr -> fast div
            const int dx = cell / (S * S) - R;
            const int dy = (cell / S) % S - R;
            const int dz = cell % S - R;
            const int X = cx + dx, Y = cy + dy, Z = cz + dz;
            if (X >= 0 && X < NC && Y >= 0 && Y < NC && Z >= 0 && Z < NC) {
                const int cid = (X * NC + Y) * NC + Z;
                int c = ccnt[cid]; if (c > CAP) c = CAP;
                const int lo = h * 8;
                const int hi = (c < lo + 8) ? c : (lo + 8);
                cnt = (hi > lo) ? (hi - lo) : 0;
                base = cid * CAP + lo;
            }
        }
        // one parallel load round: up to 8 independent scell loads per lane
        ull kv[8]; int okm = 0;
#pragma unroll
        for (int i = 0; i < 8; ++i) {
            kv[i] = 0;
            if (i < cnt) {
                const float4 cd = scell[base + i];
                const float d2 = dist2(gx, gy, gz, cd);
                if (d2 < m2eff) { okm |= (1 << i); kv[i] = packKey(d2, __float_as_int(cd.w)); }
            }
        }
        int myc = __popc(okm);
        int incl = myc;
        for (int d = 1; d < 64; d <<= 1) {
            int v = __shfl_up(incl, d);
            if (t >= d) incl += v;
        }
        int pos = total + (incl - myc);
        total += __shfl(incl, 63);
#pragma unroll
        for (int i = 0; i < 8; ++i) {
            if (okm & (1 << i)) {
                if (pos < SURV) skey[pos] = kv[i];
                ++pos;
            }
        }
        if (total > SURV) return total;   // overflow -> exactness net
    }

    // cell-overflow points (few; usually zero)
    for (int i0 = 0; i0 < novf; i0 += 64) {
        const int i = i0 + t;
        bool act = (i < novf);
        ull key = 0;
        if (act) {
            const float4 cd = ovf[i];
            const float d2 = dist2(gx, gy, gz, cd);
            act = (d2 < m2eff);
            if (act) key = packKey(d2, __float_as_int(cd.w));
        }
        const ull b = __ballot(act);
        const int p2 = total + (int)__popcll(b & ((1ull << t) - 1ull));
        if (act && p2 < SURV) skey[p2] = key;
        total += (int)__popcll(b);
    }
    return total;
}

// Exact global ranks: each lane's <=NV survivors vs all j, single u64
// compare per j. skey[j] reads are wave-uniform -> LDS broadcast.
template<int NV>
__device__ void rankEmit(int t, int n, const ull* __restrict__ skey, int g,
                         int* __restrict__ idx_out, float* __restrict__ w_out,
                         int* __restrict__ scnt, int2* __restrict__ edge,
                         int4* __restrict__ eovf, int* __restrict__ neovf)
{
    // single wave: LDS fence is enough (no full barrier round-trip)
    asm volatile("s_waitcnt lgkmcnt(0)" ::: "memory");
    ull ki[NV]; int rk[NV]; int nv = 0;
    for (int i = t; i < n && nv < NV; i += 64) { ki[nv] = skey[i]; rk[nv] = 0; ++nv; }
    for (int j = 0; j < n; ++j) {
        const ull kj = skey[j];
#pragma unroll
        for (int q = 0; q < NV; ++q)
            if (q < nv) rk[q] += (kj < ki[q]) ? 1 : 0;
    }
#pragma unroll
    for (int q = 0; q < NV; ++q)
        if (q < nv && rk[q] < KK)
            emitEdge(g, ki[q], rk[q], idx_out, w_out, scnt, edge, eovf, neovf);
}

// ---------------------------------------------------------------------------
// Exactness net (probability ~0): wave-local brute force over all N_S
// points — per-lane guarded sorted insert + 16 destructive wave-min
// butterflies. Barrier-free (safe in per-wave-divergent multi-wave blocks).
// ---------------------------------------------------------------------------
__attribute__((noinline))
__device__ void knn_brute(int g, int t, int bf,
                          const void* pos_g, const void* pos_s,
                          int* __restrict__ idx_out, float* __restrict__ w_out,
                          int* __restrict__ scnt, int2* __restrict__ edge,
                          int4* __restrict__ eovf, int* __restrict__ neovf)
{
    const float gx = ldIn(pos_g, 3 * g + 0, bf);
    const float gy = ldIn(pos_g, 3 * g + 1, bf);
    const float gz = ldIn(pos_g, 3 * g + 2, bf);

    ull bk[KK];
#pragma unroll
    for (int j = 0; j < KK; ++j) bk[j] = INF_KEY;

    for (int i = t; i < N_S; i += 64) {
        const float dx = gx - ldIn(pos_s, 3 * i + 0, bf);
        const float dy = gy - ldIn(pos_s, 3 * i + 1, bf);
        const float dz = gz - ldIn(pos_s, 3 * i + 2, bf);
        const float d2 = fmaf(dx, dx, fmaf(dy, dy, dz * dz));
        ins16(packKey(d2, i), bk);
    }

    ull myKey = INF_KEY;
    for (int p = 0; p < KK; ++p) {
        ull key = bk[0];
        for (int d = 1; d < 64; d <<= 1) {
            const ull ok = __shfl_xor(key, d);
            if (ok < key) key = ok;
        }
        if (t == p) myKey = key;
        if (bk[0] == key) {        // unique sids -> unique keys
#pragma unroll
            for (int j = 0; j < KK - 1; ++j) bk[j] = bk[j + 1];
            bk[KK - 1] = INF_KEY;
        }
    }
    if (t < KK)
        emitEdge(g, myKey, t, idx_out, w_out, scnt, edge, eovf, neovf);
}

// One kNN node, one wave, barrier-free.
__device__ void knn_task(int g, int t, int bf,
                         const void* pos_g, const void* pos_s,
                         const int* __restrict__ ccnt,
                         const float4* __restrict__ scell,
                         const float4* __restrict__ ovf, int novf,
                         int* __restrict__ idx, float* __restrict__ w,
                         int* __restrict__ scnt, int2* __restrict__ edge,
                         int4* __restrict__ eovf, int* __restrict__ neovf,
                         ull* __restrict__ skey)
{
    const float gx = ldIn(pos_g, 3 * g + 0, bf);
    const float gy = ldIn(pos_g, 3 * g + 1, bf);
    const float gz = ldIn(pos_g, 3 * g + 2, bf);
    const int cx = cellOf(gx), cy = cellOf(gy), cz = cellOf(gz);

    int total = scanR<1>(t, gx, gy, gz, cx, cy, cz,
                         regionM2f<1>(gx, gy, gz, cx, cy, cz),
                         ccnt, scell, ovf, novf, skey);
    if (total < KK)                      // clipped sphere near box face
        total = scanR<2>(t, gx, gy, gz, cx, cy, cz,
                         regionM2f<2>(gx, gy, gz, cx, cy, cz),
                         ccnt, scell, ovf, novf, skey);

    if (total >= KK && total <= SURV) {
        if (total <= 192)
            rankEmit<3>(t, total, skey, g, idx, w, scnt, edge, eovf, neovf);
        else
            rankEmit<6>(t, total, skey, g, idx, w, scnt, edge, eovf, neovf);
    } else {                             // exactness net (~never)
        knn_brute(g, t, bf, pos_g, pos_s, idx, w, scnt, edge, eovf, neovf);
    }
}

// ---- MFMA helpers -------------------------------------------------------
__device__ __forceinline__ v8s loadA_bf16(const unsigned short* p) {
    return *(const v8s*)p;
}
__device__ __forceinline__ v8s loadA_f32v(const float* f) {
    const float4 a = *(const float4*)f;
    const float4 b = *(const float4*)(f + 4);
    v8s r;
    r[0] = (short)f2bf(a.x); r[1] = (short)f2bf(a.y);
    r[2] = (short)f2bf(a.z); r[3] = (short)f2bf(a.w);
    r[4] = (short)f2bf(b.x); r[5] = (short)f2bf(b.y);
    r[6] = (short)f2bf(b.z); r[7] = (short)f2bf(b.w);
    return r;
}
__device__ __forceinline__ v8s loadA_raw(const void* A, size_t off, int bf) {
    if (bf) return loadA_bf16((const unsigned short*)A + off);
    return loadA_f32v((const float*)A + off);
}

// pre tile, ONE WAVE: 16 rows x 128 cols, K=128. Barrier-free.
__device__ void pre_tile16(int task, int lane, int bf, const void* xs, const void* xg,
                           const unsigned short* __restrict__ wpk_ps,
                           const unsigned short* __restrict__ wpk_pg,
                           unsigned short* __restrict__ hsb,
                           unsigned short* __restrict__ hgb)
{
    const void* A; const unsigned short* wpk; unsigned short* outp; int M, m0;
    const bool is_s = (task < NBS16);
    if (is_s) { A = xs; wpk = wpk_ps; outp = hsb; M = N_S; m0 = task * 16; }
    else      { A = xg; wpk = wpk_pg; outp = hgb; M = N_G; m0 = (task - NBS16) * 16; }

    const int q = lane >> 4, lm = lane & 15;
    const int mrow = m0 + lm;
    const bool valid = (mrow < M);

    v4f acc[8];
#pragma unroll
    for (int t = 0; t < 8; ++t) acc[t] = {0.f, 0.f, 0.f, 0.f};
    for (int ks = 0; ks < 4; ++ks) {
        v8s a = {0,0,0,0,0,0,0,0};
        if (valid) a = loadA_raw(A, (size_t)mrow * 128 + ks * 32 + q * 8, bf);
        const unsigned short* wb = wpk + (size_t)(ks * 4 + q) * 128 * 8;
#pragma unroll
        for (int t = 0; t < 8; ++t) {
            const v8s bfr = *(const v8s*)(wb + (t * 16 + lm) * 8);
            acc[t] = __builtin_amdgcn_mfma_f32_16x16x32_bf16(a, bfr, acc[t], 0, 0, 0);
        }
    }
#pragma unroll
    for (int t = 0; t < 8; ++t)
#pragma unroll
        for (int r = 0; r < 4; ++r) {
            const int row = m0 + q * 4 + r;
            if (row < M) outp[(size_t)row * 128 + t * 16 + lm] = f2bf(acc[t][r]);
        }
}

// post tile: 64 rows x 128 cols, K=256, 256 threads (4 waves).
// A2 (rows 128..255 of the concat) is built ONCE per lane into registers
// (all four 8-col slices in a single edge pass), then fed to the MFMA loop:
//   s-rows: sum over slotted incoming edges (g, w) of w * hg[g]  (hg L2-hot)
//   g-rows: sum over the node's K edges of w * hs[idx]           (gather)
__device__ void post_tile(int task, int bf,
                          const unsigned short* __restrict__ hsb,
                          const unsigned short* __restrict__ hgb,
                          const int* __restrict__ scnt,
                          const int2* __restrict__ edge,
                          const int4* __restrict__ eovf, int nov2,
                          const int* __restrict__ idx, const float* __restrict__ w,
                          const unsigned short* __restrict__ wpk_cs,
                          const unsigned short* __restrict__ wpk_cg,
                          void* out)
{
    const unsigned short* A1; const unsigned short* wpk;
    int M, m0, ooff;
    const bool is_s = (task < NBS);
    if (is_s) { A1 = hsb; wpk = wpk_cs; M = N_S; m0 = task * 64; ooff = 0; }
    else      { A1 = hgb; wpk = wpk_cg; M = N_G; m0 = (task - NBS) * 64; ooff = N_S * DD; }

    const int wave = threadIdx.x >> 6, lane = threadIdx.x & 63;
    const int q = lane >> 4, lm = lane & 15;
    const int mb = m0 + wave * 16;
    const int mrow = mb + lm;
    const bool valid = (mrow < M);

    // ---- build this lane's four A2 slices (cols 128 + si*32 + q*8 .. +8) ----
    v8s a2[4];
    if (valid) {
        float f[4][8];
#pragma unroll
        for (int si = 0; si < 4; ++si)
#pragma unroll
            for (int j = 0; j < 8; ++j) f[si][j] = 0.f;
        if (is_s) {
            const int c = scnt[mrow];
            const int cc = (c < ECAP) ? c : ECAP;
            for (int e = 0; e < cc; ++e) {
                const int2 ed = edge[(size_t)mrow * ECAP + e];
                const float we = __int_as_float(ed.y);
                const unsigned short* hrow = hgb + (size_t)ed.x * 128 + q * 8;
#pragma unroll
                for (int si = 0; si < 4; ++si) {
                    const v8s hv = *(const v8s*)(hrow + si * 32);
#pragma unroll
                    for (int j = 0; j < 8; ++j)
                        f[si][j] += we * bf2f((unsigned short)hv[j]);
                }
            }
            if (c > ECAP) {                // exactness net (~never)
                for (int e = 0; e < nov2; ++e) {
                    const int4 ov = eovf[e];
                    if (ov.x == mrow) {
                        const float we = __int_as_float(ov.z);
                        const unsigned short* hrow = hgb + (size_t)ov.y * 128 + q * 8;
#pragma unroll
                        for (int si = 0; si < 4; ++si) {
                            const v8s hv = *(const v8s*)(hrow + si * 32);
#pragma unroll
                            for (int j = 0; j < 8; ++j)
                                f[si][j] += we * bf2f((unsigned short)hv[j]);
                        }
                    }
                }
            }
        } else {
            for (int e = 0; e < KK; ++e) {
                const int gi = idx[mrow * KK + e];
                const float we = w[mrow * KK + e];
                const unsigned short* hrow = hsb + (size_t)gi * 128 + q * 8;
#pragma unroll
                for (int si = 0; si < 4; ++si) {
                    const v8s hv = *(const v8s*)(hrow + si * 32);
#pragma unroll
                    for (int j = 0; j < 8; ++j)
                        f[si][j] += we * bf2f((unsigned short)hv[j]);
                }
            }
        }
#pragma unroll
        for (int si = 0; si < 4; ++si) {
            v8s r;
#pragma unroll
            for (int j = 0; j < 8; ++j) r[j] = (short)f2bf(f[si][j]);
            a2[si] = r;
        }
    } else {
#pragma unroll
        for (int si = 0; si < 4; ++si) a2[si] = (v8s){0,0,0,0,0,0,0,0};
    }

    v4f acc[8];
#pragma unroll
    for (int t = 0; t < 8; ++t) acc[t] = {0.f, 0.f, 0.f, 0.f};
#pragma unroll
    for (int ks = 0; ks < 8; ++ks) {
        const int kk = ks * 32 + q * 8;
        v8s a;
        if (ks < 4) {
            a = (v8s){0,0,0,0,0,0,0,0};
            if (valid) a = loadA_bf16(A1 + (size_t)mrow * 128 + kk);
        } else {
            a = a2[ks - 4];                // compile-time index (loop unrolled)
        }
        const unsigned short* wb = wpk + (size_t)(ks * 4 + q) * 128 * 8;
#pragma unroll
        for (int t = 0; t < 8; ++t) {
            const v8s bfr = *(const v8s*)(wb + (t * 16 + lm) * 8);
            acc[t] = __builtin_amdgcn_mfma_f32_16x16x32_bf16(a, bfr, acc[t], 0, 0, 0);
        }
    }
#pragma unroll
    for (int t = 0; t < 8; ++t)
#pragma unroll
        for (int r = 0; r < 4; ++r) {
            const int row = mb + q * 4 + r;
            if (row < M) {
                float v = acc[t][r];
                if (v < 0.f) v = 0.f;
                stOut(out, ooff + row * DD + t * 16 + lm, v, bf);
            }
        }
}

// ---------------------------------------------------------------------------
// Dispatch 2: blocks 0..117 bin surface points; blocks 118..501 pack weights.
// ---------------------------------------------------------------------------
__global__ __launch_bounds__(256) void fill_pack_kernel(
    const void* pos_s, const void* pos_g,
    const void* Wsp, const void* Wgp, const void* Wgs, const void* Wsg,
    const void* Wspost, const void* Wgpost,
    int* __restrict__ ccnt, float4* __restrict__ scell,
    float4* __restrict__ ovf, int* __restrict__ novf,
    unsigned short* __restrict__ wpk_ps, unsigned short* __restrict__ wpk_pg,
    unsigned short* __restrict__ wpk_cs, unsigned short* __restrict__ wpk_cg)
{
    const int bf = detectFlag(pos_g);
    const int bid = blockIdx.x, tid = threadIdx.x;
    if (bid < FILL_BLOCKS) {
        const int p = bid * 256 + tid;
        if (p < N_S) {
            const float x = ldIn(pos_s, 3 * p + 0, bf);
            const float y = ldIn(pos_s, 3 * p + 1, bf);
            const float z = ldIn(pos_s, 3 * p + 2, bf);
            const int cid = (cellOf(x) * NC + cellOf(y)) * NC + cellOf(z);
            const int slot = atomicAdd(&ccnt[cid], 1);
            const float4 pt = make_float4(x, y, z, __int_as_float(p));
            if (slot < CAP) scell[cid * CAP + slot] = pt;
            else            ovf[atomicAdd(novf, 1)] = pt;
        }
        return;
    }
    __shared__ float rows[256];
    const int rt = bid - FILL_BLOCKS;            // 0..383
    const int half = tid >> 7, j = tid & 127;
    const int task = rt * 2 + half;              // 0..767; branch uniform per block
    float v; unsigned short* dst; int k;
    if (task < 128) { k = task; v = ldIn(Wsp, k * DD + j, bf); dst = wpk_ps; }
    else if (task < 256) { k = task - 128; v = ldIn(Wgp, k * DD + j, bf); dst = wpk_pg; }
    else {
        const int which_g = (task >= 512);
        const int r = which_g ? (task - 512) : (task - 256);
        const void* W1 = which_g ? Wsg : Wgs;
        const void* Wp = which_g ? Wgpost : Wspost;
        dst = which_g ? wpk_cg : wpk_cs;
        k = r;
        if (r < 128) v = ldIn(Wp, r * DD + j, bf);
        else {
            rows[half * 128 + j] = ldIn(W1, (r - 128) * DD + j, bf);
            __syncthreads();
            float acc = 0.f;
            for (int m = 0; m < DD; ++m)
                acc += rows[half * 128 + m] * ldIn(Wp, (DD + m) * DD + j, bf);
            v = acc;
        }
    }
    const int ks = k >> 5, q = (k >> 3) & 3, i = k & 7;
    dst[((ks * 4 + q) * 128 + j) * 8 + i] = f2bf(v);
}

// ---------------------------------------------------------------------------
// Dispatch 3: QBLOCKS fat 4-wave blocks; each WAVE statically owns tasks
// {wid, wid + NWAVES} (3 kNN : 2 pre interleave for L2 locality). Fat
// blocks sustain ~12 waves/CU (vs ~3.5 with 5160 tiny WGs, launch-rate
// capped) and static assignment avoids round 7's serialized same-address
// atomic queue (~55 cyc/atomic x 5160 = the whole 119 us). Zero barriers,
// zero atomics in the scheduling path.
// ---------------------------------------------------------------------------
__global__ __launch_bounds__(256) void knn_pre_kernel(
    const void* xs, const void* xg, const void* pos_s, const void* pos_g,
    const int* __restrict__ ccnt, const float4* __restrict__ scell,
    const float4* __restrict__ ovf, const int* __restrict__ novf,
    int* __restrict__ idx, float* __restrict__ w,
    int* __restrict__ scnt, int2* __restrict__ edge,
    int4* __restrict__ eovf, int* __restrict__ neovf,
    const unsigned short* __restrict__ wpk_ps,
    const unsigned short* __restrict__ wpk_pg,
    unsigned short* __restrict__ hsb, unsigned short* __restrict__ hgb)
{
    __shared__ ull skey[4][SURV];
    const int bf = detectFlag(pos_g);
    const int wv = threadIdx.x >> 6, lane = threadIdx.x & 63;
    const int nov = *novf;
    const int wid = blockIdx.x * 4 + wv;        // 0..NWAVES-1

    for (int t0 = wid; t0 < TASKS; t0 += NWAVES) {
        const int grp = t0 / 5, off = t0 - grp * 5;
        if (off < 3) {
            const int g = grp * 3 + off;
            if (g < N_G)
                knn_task(g, lane, bf, pos_g, pos_s, ccnt, scell, ovf, nov,
                         idx, w, scnt, edge, eovf, neovf, skey[wv]);
        } else {
            const int task = grp * 2 + (off - 3);
            if (task < PRE_TILES)
                pre_tile16(task, lane, bf, xs, xg, wpk_ps, wpk_pg, hsb, hgb);
        }
    }
}

// Dispatch 4: post GEMMs with fused message aggregation.
__global__ __launch_bounds__(256) void mfma_post_kernel(
    const void* pos_g,
    const unsigned short* __restrict__ hsb, const unsigned short* __restrict__ hgb,
    const int* __restrict__ scnt, const int2* __restrict__ edge,
    const int4* __restrict__ eovf, const int* __restrict__ neovf,
    const int* __restrict__ idx, const float* __restrict__ w,
    const unsigned short* __restrict__ wpk_cs, const unsigned short* __restrict__ wpk_cg,
    void* out)
{
    const int bf = detectFlag(pos_g);
    int nov2 = *neovf; if (nov2 > EOVF_CAP) nov2 = EOVF_CAP;
    post_tile(blockIdx.x, bf, hsb, hgb, scnt, edge, eovf, nov2,
              idx, w, wpk_cs, wpk_cg, out);
}

extern "C" void kernel_launch(void* const* d_in, const int* in_sizes, int n_in,
                              void* d_out, int out_size, void* d_ws, size_t ws_size,
                              hipStream_t stream)
{
    const void* xs       = d_in[0];
    const void* xg       = d_in[1];
    const void* pos_s    = d_in[2];
    const void* pos_g    = d_in[3];
    const void* W_s_pre  = d_in[4];
    const void* W_g_pre  = d_in[5];
    const void* W_gs     = d_in[6];
    const void* W_sg     = d_in[7];
    const void* W_s_post = d_in[8];
    const void* W_g_post = d_in[9];
    (void)in_sizes; (void)n_in; (void)out_size; (void)ws_size;

    char* ws = (char*)d_ws;
    size_t off_b = 0;
    auto alloc = [&](size_t bytes) -> void* {
        void* p = ws + off_b;
        off_b = (off_b + bytes + 255) & ~((size_t)255);
        return p;
    };
    unsigned short* hsb    = (unsigned short*)alloc((size_t)N_S * DD * 2);
    unsigned short* hgb    = (unsigned short*)alloc((size_t)N_G * DD * 2);
    unsigned short* wpk_ps = (unsigned short*)alloc((size_t)DD * DD * 2);
    unsigned short* wpk_pg = (unsigned short*)alloc((size_t)DD * DD * 2);
    unsigned short* wpk_cs = (unsigned short*)alloc((size_t)2 * DD * DD * 2);
    unsigned short* wpk_cg = (unsigned short*)alloc((size_t)2 * DD * DD * 2);
    int*            idx    = (int*)   alloc((size_t)NE * 4);
    float*          w      = (float*) alloc((size_t)NE * 4);
    // contiguous zeroed block: ccnt | novf | scnt | neovf
    int*            ibase  = (int*)   alloc((size_t)(CELLS + 1 + N_S + 1) * 4);
    int*            ccnt   = ibase;
    int*            novf   = ibase + CELLS;
    int*            scnt   = ibase + CELLS + 1;
    int*            neovf  = ibase + CELLS + 1 + N_S;
    float4*         scell  = (float4*)alloc((size_t)CELLS * CAP * 16);
    float4*         ovf    = (float4*)alloc((size_t)N_S * 16);
    int2*           edge   = (int2*)  alloc((size_t)N_S * ECAP * 8);
    int4*           eovf   = (int4*)  alloc((size_t)EOVF_CAP * 16);

    hipMemsetAsync(ibase, 0, (size_t)(CELLS + 1 + N_S + 1) * 4, stream);

    fill_pack_kernel<<<FILL_BLOCKS + PACK_BLOCKS, 256, 0, stream>>>(
        pos_s, pos_g, W_s_pre, W_g_pre, W_gs, W_sg, W_s_post, W_g_post,
        ccnt, scell, ovf, novf, wpk_ps, wpk_pg, wpk_cs, wpk_cg);

    knn_pre_kernel<<<QBLOCKS, 256, 0, stream>>>(
        xs, xg, pos_s, pos_g, ccnt, scell, ovf, novf, idx, w,
        scnt, edge, eovf, neovf, wpk_ps, wpk_pg, hsb, hgb);

    mfma_post_kernel<<<NTILE, 256, 0, stream>>>(
        pos_g, hsb, hgb, scnt, edge, eovf, neovf, idx, w,
        wpk_cs, wpk_cg, d_out);
}